// Round 1
// baseline (6524.745 us; speedup 1.0000x reference)
//
#include <hip/hip_runtime.h>
#include <math.h>

// Dims
constexpr int BB  = 128;
constexpr int TT  = 512;
constexpr int DIN = 88;
constexpr int DZ  = 80;
constexpr int DH  = 400;
constexpr int DE  = 100;
constexpr int DTR = 200;
constexpr int DOUT = DIN + DZ + DZ; // 248

// RNN W_hh split: 100 float4 k-chunks total
constexpr int NR = 48;               // chunks held in registers per thread
constexpr int NL = 24;               // chunks held in LDS
constexpr int NG = 100 - NR - NL;    // 28 chunks streamed from L2

__device__ __forceinline__ float dot4(float4 w, float4 h, float acc) {
    return fmaf(w.x, h.x, fmaf(w.y, h.y, fmaf(w.z, h.z, fmaf(w.w, h.w, acc))));
}
__device__ __forceinline__ float softplusf(float x) {
    return fmaxf(x, 0.f) + log1pf(__expf(-fabsf(x)));
}
__device__ __forceinline__ float sigmoidf(float x) {
    return 1.f / (1.f + __expf(-x));
}

// Pack W_hh (H,H) row-major into chunked layout: Wpk[kk*400 + j] = W_hh[j][4kk..4kk+3]
__global__ void pack_kernel(const float* __restrict__ W_hh, float4* __restrict__ Wpk) {
    int idx = blockIdx.x * 256 + threadIdx.x;
    if (idx < 100 * DH) {
        int kk = idx / DH, j = idx % DH;
        const float* s = W_hh + j * DH + 4 * kk;
        Wpk[idx] = make_float4(s[0], s[1], s[2], s[3]);
    }
}

// pre[b][tt][h] = sum_k x[b][T-1-tt][k]*W_ih[h][k] + b_ih[h] + b_hh[h]
__global__ __launch_bounds__(256) void pre_kernel(
    const float* __restrict__ x, const float* __restrict__ W_ih,
    const float* __restrict__ b_ih, const float* __restrict__ b_hh,
    float* __restrict__ pre) {
    int b = blockIdx.y;
    int tt0 = blockIdx.x * 8;
    __shared__ float xs[8][DIN];
    int tid = threadIdx.x;
    for (int idx = tid; idx < 8 * DIN; idx += 256) {
        int r = idx / DIN, k = idx % DIN;
        int tsrc = TT - 1 - (tt0 + r);
        xs[r][k] = x[(b * TT + tsrc) * DIN + k];
    }
    __syncthreads();
    for (int h = tid; h < DH; h += 256) {
        float bias = b_ih[h] + b_hh[h];
        float acc[8];
        #pragma unroll
        for (int r = 0; r < 8; ++r) acc[r] = bias;
        #pragma unroll
        for (int kk = 0; kk < DIN / 4; ++kk) {
            float4 w = *(const float4*)(W_ih + h * DIN + 4 * kk);
            #pragma unroll
            for (int r = 0; r < 8; ++r) {
                float4 xv = *(const float4*)(&xs[r][4 * kk]);
                acc[r] = dot4(w, xv, acc[r]);
            }
        }
        for (int r = 0; r < 8; ++r)
            pre[(size_t)(b * TT + tt0 + r) * DH + h] = acc[r];
    }
}

// Serial scan: h_t = relu(pre_t + W_hh h_{t-1}); writes h_t in-place over pre_t.
// One block per batch row. W cached: NR chunks in regs, NL in LDS, NG from L2.
__global__ __launch_bounds__(512, 2) void rnn_kernel(
    const float4* __restrict__ Wpk, const float* __restrict__ h0,
    float* __restrict__ hs) {
    extern __shared__ float4 smem4[];
    float4* Wl  = smem4;                         // NL*400 float4
    float* hcur = (float*)(smem4 + NL * DH);     // 400 floats, 16B aligned
    int b = blockIdx.x;
    int tid = threadIdx.x;

    float4 Wreg[NR];
    if (tid < DH) {
        #pragma unroll
        for (int c = 0; c < NR; ++c) Wreg[c] = Wpk[c * DH + tid];
    }
    for (int i = tid; i < NL * DH; i += 512) Wl[i] = Wpk[NR * DH + i];
    if (tid < DH) hcur[tid] = h0[tid];
    __syncthreads();

    float* base = hs + (size_t)b * TT * DH;
    for (int tt = 0; tt < TT; ++tt) {
        float acc = 0.f;
        if (tid < DH) {
            acc = base[tt * DH + tid];
            #pragma unroll
            for (int c = 0; c < NR; ++c) {
                float4 h4 = *(const float4*)(hcur + 4 * c);
                acc = dot4(Wreg[c], h4, acc);
            }
            #pragma unroll
            for (int c = 0; c < NL; ++c) {
                float4 w  = Wl[c * DH + tid];
                float4 h4 = *(const float4*)(hcur + 4 * (NR + c));
                acc = dot4(w, h4, acc);
            }
            #pragma unroll
            for (int c = 0; c < NG; ++c) {
                float4 w  = Wpk[(NR + NL + c) * DH + tid];
                float4 h4 = *(const float4*)(hcur + 4 * (NR + NL + c));
                acc = dot4(w, h4, acc);
            }
        }
        __syncthreads();
        if (tid < DH) {
            float v = fmaxf(acc, 0.f);
            hcur[tid] = v;
            base[tt * DH + tid] = v;
        }
        __syncthreads();
    }
}

// Fused downstream: per (b, 8-t chunk): z (incl. t-1 row), gate/prop/trans, emission.
__global__ __launch_bounds__(256) void e_kernel(
    const float* __restrict__ hs, const float* __restrict__ eps,
    const float* __restrict__ z0,
    const float* __restrict__ W_loc, const float* __restrict__ b_loc,
    const float* __restrict__ W_scale, const float* __restrict__ b_scale,
    const float* __restrict__ gW1, const float* __restrict__ gb1,
    const float* __restrict__ gW2, const float* __restrict__ gb2,
    const float* __restrict__ pW1, const float* __restrict__ pb1,
    const float* __restrict__ pW2, const float* __restrict__ pb2,
    const float* __restrict__ sW, const float* __restrict__ sb,
    const float* __restrict__ lW, const float* __restrict__ lb,
    const float* __restrict__ eW1, const float* __restrict__ eb1,
    const float* __restrict__ eW2, const float* __restrict__ eb2,
    const float* __restrict__ eW3, const float* __restrict__ eb3,
    float* __restrict__ out) {
    __shared__ float hsr[9][DH];       // rnn_out rows for t in [t0-1, t0+7]
    __shared__ float zst[2][9][DZ];    // z_loc / z_scale pre-activations
    __shared__ float zl[9][DZ];        // z rows (zl[0] = z_shift boundary)
    __shared__ float A[8][DTR];
    __shared__ float P[8][DTR];
    __shared__ float gate[8][DZ];
    __shared__ float prop[8][DZ];
    __shared__ float h1[8][DE];
    __shared__ float h2[8][DE];

    int b = blockIdx.y;
    int t0 = blockIdx.x * 8;
    int tid = threadIdx.x;
    int r0 = (t0 == 0) ? 1 : 0;

    // P0: stage rnn_out rows (hs index T-1-t)
    for (int idx = tid; idx < 9 * DH; idx += 256) {
        int r = idx / DH, k = idx % DH;
        int t = t0 - 1 + r;
        if (t >= 0) hsr[r][k] = hs[((size_t)b * TT + (TT - 1 - t)) * DH + k];
    }
    __syncthreads();

    // P1: z_loc / z_scale pre-activations
    if (tid < 2 * DZ) {
        int part = tid / DZ, o = tid % DZ;
        const float* Wrow = (part ? W_scale : W_loc) + o * DH;
        float bias = part ? b_scale[o] : b_loc[o];
        for (int r = r0; r < 9; ++r) {
            float acc = bias;
            #pragma unroll
            for (int kk = 0; kk < DH / 4; ++kk) {
                float4 w  = *(const float4*)(Wrow + 4 * kk);
                float4 hv = *(const float4*)(&hsr[r][4 * kk]);
                acc = dot4(w, hv, acc);
            }
            zst[part][r][o] = acc;
        }
    }
    __syncthreads();

    // P1b: z = z_loc + softplus(z_scale_pre) * eps   (row -1 -> z0)
    for (int idx = tid; idx < 9 * DZ; idx += 256) {
        int r = idx / DZ, o = idx % DZ;
        int t = t0 - 1 + r;
        float zv;
        if (t < 0) zv = z0[o];
        else {
            float sp = softplusf(zst[1][r][o]);
            zv = zst[0][r][o] + sp * eps[((size_t)b * TT + t) * DZ + o];
        }
        zl[r][o] = zv;
    }
    __syncthreads();

    // P2: A = relu(zs@gW1^T+gb1), P = relu(zs@pW1^T+pb1); zs row for t=t0+r is zl[r]
    if (tid < DTR) {
        int o = tid;
        const float* g = gW1 + o * DZ;
        const float* p = pW1 + o * DZ;
        float bg = gb1[o], bp = pb1[o];
        for (int r = 0; r < 8; ++r) {
            float ag = bg, ap = bp;
            #pragma unroll
            for (int kk = 0; kk < DZ / 4; ++kk) {
                float4 zv = *(const float4*)(&zl[r][4 * kk]);
                float4 wg = *(const float4*)(g + 4 * kk);
                float4 wp = *(const float4*)(p + 4 * kk);
                ag = dot4(wg, zv, ag);
                ap = dot4(wp, zv, ap);
            }
            A[r][o] = fmaxf(ag, 0.f);
            P[r][o] = fmaxf(ap, 0.f);
        }
    }
    __syncthreads();

    // P3: gate = sigmoid(A@gW2^T+gb2), prop = P@pW2^T+pb2
    for (int idx = tid; idx < 8 * DZ; idx += 256) {
        int r = idx / DZ, o = idx % DZ;
        float ag = gb2[o], ap = pb2[o];
        const float* g = gW2 + o * DTR;
        const float* p = pW2 + o * DTR;
        #pragma unroll
        for (int kk = 0; kk < DTR / 4; ++kk) {
            float4 av = *(const float4*)(&A[r][4 * kk]);
            float4 pv = *(const float4*)(&P[r][4 * kk]);
            float4 wg = *(const float4*)(g + 4 * kk);
            float4 wp = *(const float4*)(p + 4 * kk);
            ag = dot4(wg, av, ag);
            ap = dot4(wp, pv, ap);
        }
        gate[r][o] = sigmoidf(ag);
        prop[r][o] = ap;
    }
    __syncthreads();

    // P4: trans_loc / trans_scale -> out[88..248)
    for (int idx = tid; idx < 8 * DZ; idx += 256) {
        int r = idx / DZ, o = idx % DZ;
        int t = t0 + r;
        float al = lb[o], as_ = sb[o];
        const float* lw = lW + o * DZ;
        const float* sw = sW + o * DZ;
        #pragma unroll
        for (int kk = 0; kk < DZ / 4; ++kk) {
            float4 zv = *(const float4*)(&zl[r][4 * kk]);
            float4 wl = *(const float4*)(lw + 4 * kk);
            al = dot4(wl, zv, al);
            float4 pv = *(const float4*)(&prop[r][4 * kk]);
            pv.x = fmaxf(pv.x, 0.f); pv.y = fmaxf(pv.y, 0.f);
            pv.z = fmaxf(pv.z, 0.f); pv.w = fmaxf(pv.w, 0.f);
            float4 ws_ = *(const float4*)(sw + 4 * kk);
            as_ = dot4(ws_, pv, as_);
        }
        float g = gate[r][o];
        float tl = (1.f - g) * al + g * prop[r][o];
        size_t ob = ((size_t)b * TT + t) * DOUT;
        out[ob + DIN + o]      = tl;
        out[ob + DIN + DZ + o] = softplusf(as_);
    }
    __syncthreads();

    // P5: h1 = relu(z@eW1^T+eb1); z for t=t0+r is zl[r+1]
    for (int idx = tid; idx < 8 * DE; idx += 256) {
        int r = idx / DE, o = idx % DE;
        float a = eb1[o];
        const float* w = eW1 + o * DZ;
        #pragma unroll
        for (int kk = 0; kk < DZ / 4; ++kk) {
            float4 zv = *(const float4*)(&zl[r + 1][4 * kk]);
            float4 wv = *(const float4*)(w + 4 * kk);
            a = dot4(wv, zv, a);
        }
        h1[r][o] = fmaxf(a, 0.f);
    }
    __syncthreads();

    // P6: h2 = relu(h1@eW2^T+eb2)
    for (int idx = tid; idx < 8 * DE; idx += 256) {
        int r = idx / DE, o = idx % DE;
        float a = eb2[o];
        const float* w = eW2 + o * DE;
        #pragma unroll
        for (int kk = 0; kk < DE / 4; ++kk) {
            float4 hv = *(const float4*)(&h1[r][4 * kk]);
            float4 wv = *(const float4*)(w + 4 * kk);
            a = dot4(wv, hv, a);
        }
        h2[r][o] = fmaxf(a, 0.f);
    }
    __syncthreads();

    // P7: emis = sigmoid(h2@eW3^T+eb3) -> out[0..88)
    for (int idx = tid; idx < 8 * DIN; idx += 256) {
        int r = idx / DIN, o = idx % DIN;
        float a = eb3[o];
        const float* w = eW3 + o * DE;
        #pragma unroll
        for (int kk = 0; kk < DE / 4; ++kk) {
            float4 hv = *(const float4*)(&h2[r][4 * kk]);
            float4 wv = *(const float4*)(w + 4 * kk);
            a = dot4(wv, hv, a);
        }
        out[((size_t)b * TT + t0 + r) * DOUT + o] = sigmoidf(a);
    }
}

extern "C" void kernel_launch(void* const* d_in, const int* in_sizes, int n_in,
                              void* d_out, int out_size, void* d_ws, size_t ws_size,
                              hipStream_t stream) {
    const float* x       = (const float*)d_in[0];
    const float* eps     = (const float*)d_in[1];
    const float* W_ih    = (const float*)d_in[2];
    const float* W_hh    = (const float*)d_in[3];
    const float* b_ih    = (const float*)d_in[4];
    const float* b_hh    = (const float*)d_in[5];
    const float* h0      = (const float*)d_in[6];
    const float* z0      = (const float*)d_in[7];
    const float* W_loc   = (const float*)d_in[8];
    const float* b_loc   = (const float*)d_in[9];
    const float* W_scale = (const float*)d_in[10];
    const float* b_scale = (const float*)d_in[11];
    const float* gW1 = (const float*)d_in[12];
    const float* gb1 = (const float*)d_in[13];
    const float* gW2 = (const float*)d_in[14];
    const float* gb2 = (const float*)d_in[15];
    const float* pW1 = (const float*)d_in[16];
    const float* pb1 = (const float*)d_in[17];
    const float* pW2 = (const float*)d_in[18];
    const float* pb2 = (const float*)d_in[19];
    const float* sW  = (const float*)d_in[20];
    const float* sb  = (const float*)d_in[21];
    const float* lW  = (const float*)d_in[22];
    const float* lb  = (const float*)d_in[23];
    const float* eW1 = (const float*)d_in[24];
    const float* eb1 = (const float*)d_in[25];
    const float* eW2 = (const float*)d_in[26];
    const float* eb2 = (const float*)d_in[27];
    const float* eW3 = (const float*)d_in[28];
    const float* eb3 = (const float*)d_in[29];

    float* wsf = (float*)d_ws;
    float* prebuf = wsf;                               // B*T*H floats
    float4* Wpk = (float4*)(wsf + (size_t)BB * TT * DH); // 100*400 float4 (16B-aligned)
    float* outf = (float*)d_out;

    pack_kernel<<<(100 * DH + 255) / 256, 256, 0, stream>>>(W_hh, Wpk);
    pre_kernel<<<dim3(TT / 8, BB), 256, 0, stream>>>(x, W_ih, b_ih, b_hh, prebuf);

    size_t smem = (size_t)NL * DH * sizeof(float4) + DH * sizeof(float);
    hipFuncSetAttribute((const void*)rnn_kernel,
                        hipFuncAttributeMaxDynamicSharedMemorySize, (int)smem);
    rnn_kernel<<<dim3(BB), dim3(512), smem, stream>>>(Wpk, h0, prebuf);

    e_kernel<<<dim3(TT / 8, BB), 256, 0, stream>>>(
        prebuf, eps, z0, W_loc, b_loc, W_scale, b_scale,
        gW1, gb1, gW2, gb2, pW1, pb1, pW2, pb2, sW, sb, lW, lb,
        eW1, eb1, eW2, eb2, eW3, eb3, outf);
}